// Round 10
// baseline (641.467 us; speedup 1.0000x reference)
//
#include <hip/hip_runtime.h>
#include <cmath>

// ---------------------------------------------------------------------------
// 6x (conv3x3+BN+ReLU) -> LSTM(4096->256) over S=64 -> tanh(linear).
// R9: convs L1..L5 ported to split-bf16 MFMA implicit-GEMM (hh+hl+lh, proven
// absmax 3e-8). L0 (K=27) stays fp32.
// LSTM ledger (measured):
//  R14 94us (base: 128 blk x 1024 thr, 8 pollers/word, 2 barriers/step)
//  R12 356us all-to-all coupling / R16 111us LDS weights / R17 124us
//   (scalar arrays remat even at 4 waves; 16 pollers/word +0.5us/step).
//  R18 94.5us, total 471 (best): pre-poll asm pin DID hoist the loads
//   (VGPR 32->52, VALUBusy 20%) but "+v" pin = s_waitcnt vmcnt(0) BEFORE
//   the poll -> the 0.85us weight drain moved ahead of the 0.5us poll,
//   still serial. Step = drain + poll + compute = 1.47us, unchanged.
// R19: true issue/wait split (T14 async-STAGE pattern). Weights loaded via
// raw inline-asm global_load_dwordx4 (no implicit waitcnt, invisible to the
// compiler's vmcnt bookkeeping -- its own counted waits then only OVERcount,
// which is safe), poll runs with loads in flight, then explicit
// s_waitcnt vmcnt(0) + sched_barrier(0) (rule #18) before the matvec.
// Drain overlaps poll: step ~= max(0.85, 0.5) + 0.3. waves_per_eu(4,4)
// relaxes the VGPR budget to 128 so the 32 asm-held regs survive the poll
// (128 blocks = 1 block/CU; capping occupancy costs nothing). Both
// branches drain vmcnt before loop-bottom (no WAW on re-issue).
// ---------------------------------------------------------------------------

typedef __attribute__((ext_vector_type(8))) __bf16 bf16x8;
typedef __attribute__((ext_vector_type(4))) float f32x4;

__device__ __forceinline__ float sigmoidf_(float x) { return 1.f / (1.f + expf(-x)); }

__device__ __forceinline__ float fsig_(float x) {
  return __builtin_amdgcn_rcpf(1.f + __expf(-x));
}
__device__ __forceinline__ float ftanh_(float x) {
  float xc = fminf(fmaxf(x, -15.f), 15.f);
  float e = __expf(2.f * xc);
  return (e - 1.f) * __builtin_amdgcn_rcpf(e + 1.f);
}

__device__ __forceinline__ unsigned short f2bf(float f) {   // RNE
  unsigned u = __float_as_uint(f);
  unsigned r = (u + 0x7fffu + ((u >> 16) & 1u)) >> 16;
  return (unsigned short)r;
}
__device__ __forceinline__ float bf2f(unsigned short h) {
  return __uint_as_float(((unsigned)h) << 16);
}

// ---------------- fold BN into conv weights (fp32 path + bias) ----------
struct FoldPack {
  const float *w[6], *g[6], *b[6], *m[6], *v[6];
  float *wf[6], *bias[6];
  int oc[6], ic[6];
};

__global__ __launch_bounds__(256) void fold_all(FoldPack p) {
  const int layer = blockIdx.y;
  const int OC = p.oc[layer], IC = p.ic[layer];
  const int total = OC * IC * 9;
  const float* w = p.w[layer];
  float* wf = p.wf[layer];
  for (int i = blockIdx.x * 256 + threadIdx.x; i < total; i += gridDim.x * 256) {
    int oc = i / (IC * 9);
    int r  = i % (IC * 9);
    int ic = r / 9;
    int k  = r % 9;
    int ky = k / 3, kx = k % 3;
    float inv = p.g[layer][oc] / sqrtf(p.v[layer][oc] + 1e-5f);
    wf[(((ic * 3 + ky) * OC) + oc) * 4 + kx] = w[i] * inv;
  }
  if (blockIdx.x == 0) {
    int i = threadIdx.x;
    if (i < OC) {
      float inv = p.g[layer][i] / sqrtf(p.v[layer][i] + 1e-5f);
      p.bias[layer][i] = p.b[layer][i] - p.m[layer][i] * inv;
    }
  }
}

// ---------------- pack BN-folded weights into MFMA A-frag layout ----------
// A[m=oc][k], k = tap*IC + ic (tap-major). Layout: [mt*KG+g][lane(64)][8]
// where lane -> (m = mt*16 + (lane&15), k = 32g + 8*(lane>>4) + j).
// k >= Kreal -> 0 (zero tap-9 padding for IC=16 layers). bf16 hi + lo.
struct PackPack {
  const float *w[5], *g[5], *v[5];
  unsigned short *wh[5], *wl[5];
  int ic[5], oc[5], kg[5], kreal[5];
};

__global__ __launch_bounds__(256) void pack_w(PackPack p) {
  const int layer = blockIdx.y;
  const int IC = p.ic[layer], KG = p.kg[layer], K = p.kreal[layer];
  const int MT = p.oc[layer] / 16;
  const int total = MT * KG * 512;
  for (int i = blockIdx.x * 256 + threadIdx.x; i < total; i += gridDim.x * 256) {
    int j = i & 7;
    int lane = (i >> 3) & 63;
    int gmt = i >> 9;               // = mt*KG + g
    int m = (gmt / KG) * 16 + (lane & 15);
    int k = 32 * (gmt % KG) + 8 * (lane >> 4) + j;
    float val = 0.f;
    if (k < K) {
      int tap = k / IC, ic = k % IC;
      int ky = tap / 3, kx = tap % 3;
      float inv = p.g[layer][m] / sqrtf(p.v[layer][m] + 1e-5f);
      val = p.w[layer][((m * IC + ic) * 3 + ky) * 3 + kx] * inv;
    }
    unsigned short h = f2bf(val);
    p.wh[layer][i] = h;
    p.wl[layer][i] = f2bf(val - bf2f(h));
  }
}

// ---------------- fp32 direct conv (L0 only: IC=3, K=27) ----------------
template<int IC, int OC, int IH, int IW, int STRIDE, int TPOS, int SPLITY,
         int ICS, int MINW>
__global__ __launch_bounds__(256, MINW) void conv_bn_relu(
    const float* __restrict__ in, const float* __restrict__ wf,
    const float* __restrict__ bias, float* __restrict__ out)
{
  constexpr int OH = IH / STRIDE, OW = IW / STRIDE;
  constexpr int OHB = OH / SPLITY;
  constexpr int RIH = (SPLITY == 1) ? (IH + 2) : ((OHB - 1) * STRIDE + 3);
  constexpr int PIW = IW + 4;
  constexpr int PLANE = RIH * PIW;
  constexpr int NPOS = OHB * OW;
  constexpr int WPOS = NPOS / TPOS;
  constexpr int SLOT = WPOS * ICS;
  constexpr int GROUPS = 256 / SLOT;
  constexpr int TOC = OC / GROUPS;
  constexpr int CH = IC / ICS;
  constexpr int SPAN = (TPOS - 1) * STRIDE + 3;
  constexpr int NW = (SPAN + 3) / 4;
  constexpr int XSLOTS = OW / TPOS;
  static_assert(SLOT % 64 == 0 && GROUPS * SLOT == 256 && GROUPS * TOC == OC, "tiling");

  __shared__ float s_in[IC * PLANE];

  const int tid = threadIdx.x;
  const int n     = (SPLITY == 1) ? blockIdx.x : blockIdx.x / SPLITY;
  const int split = (SPLITY == 1) ? 0 : blockIdx.x % SPLITY;
  const int ry0 = split * OHB;
  const int r0  = ry0 * STRIDE - 1;

  for (int i = tid; i < IC * PLANE / 4; i += 256)
    ((float4*)s_in)[i] = float4{0.f, 0.f, 0.f, 0.f};
  __syncthreads();

  constexpr int ROWF4 = IW / 4;
  constexpr int NSTG = IC * RIH * ROWF4;
  for (int i = tid; i < NSTG; i += 256) {
    int rw  = i % ROWF4;
    int t   = i / ROWF4;
    int row = t % RIH;
    int ic  = t / RIH;
    int giy = r0 + row;
    if (giy >= 0 && giy < IH) {
      float4 v = *(const float4*)(in + ((size_t)(n * IC + ic) * IH + giy) * IW + rw * 4);
      float* dst = &s_in[(ic * RIH + row) * PIW + 1 + rw * 4];
      dst[0] = v.x; dst[1] = v.y; dst[2] = v.z; dst[3] = v.w;
    }
  }
  __syncthreads();

  const int group  = tid / SLOT;
  const int sl     = tid % SLOT;
  const int icq    = sl / WPOS;
  const int worker = sl % WPOS;
  const int oy  = worker / XSLOTS;
  const int ox0 = (worker % XSLOTS) * TPOS;
  const int xb  = ox0 * STRIDE;

  const int oc0u = __builtin_amdgcn_readfirstlane(group * TOC);
  const float4* wg = (const float4*)wf + oc0u;

  float acc[TOC][TPOS];
  #pragma unroll
  for (int a = 0; a < TOC; ++a)
    #pragma unroll
    for (int p = 0; p < TPOS; ++p) acc[a][p] = 0.f;

  for (int icl = 0; icl < CH; ++icl) {
    const int ic = icq * CH + icl;
    const float* sI = &s_in[ic * PLANE];
    #pragma unroll
    for (int ky = 0; ky < 3; ++ky) {
      float row[NW * 4];
      {
        const float4* rp = (const float4*)&sI[(oy * STRIDE + ky) * PIW + xb];
        #pragma unroll
        for (int w = 0; w < NW; ++w) {
          float4 t4 = rp[w];
          row[4*w+0] = t4.x; row[4*w+1] = t4.y;
          row[4*w+2] = t4.z; row[4*w+3] = t4.w;
        }
      }
      const float4* wrow = wg + (ic * 3 + ky) * OC;
      #pragma unroll
      for (int oc = 0; oc < TOC; ++oc) {
        float4 w4 = wrow[oc];
        #pragma unroll
        for (int p = 0; p < TPOS; ++p)
          acc[oc][p] = fmaf(row[p * STRIDE + 0], w4.x,
                       fmaf(row[p * STRIDE + 1], w4.y,
                       fmaf(row[p * STRIDE + 2], w4.z, acc[oc][p])));
      }
    }
  }

  #pragma unroll
  for (int d = WPOS; d < SLOT; d <<= 1)
    #pragma unroll
    for (int oc = 0; oc < TOC; ++oc)
      #pragma unroll
      for (int p = 0; p < TPOS; ++p)
        acc[oc][p] += __shfl_xor(acc[oc][p], d);

  if (icq == 0) {
    float* outN = out + (size_t)n * (OC * OH * OW);
    #pragma unroll
    for (int oc = 0; oc < TOC; ++oc) {
      const float bb = bias[oc0u + oc];
      float* op = outN + ((size_t)(oc0u + oc) * OH + (ry0 + oy)) * OW + ox0;
      #pragma unroll
      for (int vq = 0; vq < TPOS / 4; ++vq) {
        float4 val;
        val.x = fmaxf(acc[oc][vq*4+0] + bb, 0.f);
        val.y = fmaxf(acc[oc][vq*4+1] + bb, 0.f);
        val.z = fmaxf(acc[oc][vq*4+2] + bb, 0.f);
        val.w = fmaxf(acc[oc][vq*4+3] + bb, 0.f);
        *(float4*)(op + vq * 4) = val;
      }
    }
  }
}

// ---------------- MFMA implicit-GEMM conv (L1..L5) ----------------
// M=OC (A=packed weights, global), N=positions (B=input, LDS NHWC bf16 h/l),
// K=IC*9 (padded to KG*32). C row=oc (quad*4+reg), col=pos (lane&15).
template<int IC, int OC, int IH, int IW, int STRIDE, int SPLITY, int KG, int ZROW>
__global__ __launch_bounds__(256, 2) void conv_mfma(
    const float* __restrict__ in, const unsigned short* __restrict__ Ah,
    const unsigned short* __restrict__ Al, const float* __restrict__ bias,
    float* __restrict__ out)
{
  constexpr int OH = IH / STRIDE, OW = IW / STRIDE;
  constexpr int OHB = OH / SPLITY;
  constexpr int N = OHB * OW;
  constexpr int NT = N / 16;
  constexpr int NTW = NT / 4;              // n-tiles per wave
  constexpr int MT = OC / 16;
  constexpr int ICP = IC + 8;              // bank-skew pad (2-way worst, stride1)
  constexpr int PW = IW + 3;
  constexpr int PH = (OHB - 1) * STRIDE + 3 + ZROW;
  constexpr int SZ = ((PH * PW * ICP + 7) / 8) * 8;
  static_assert(NT % 4 == 0, "nt");

  __shared__ unsigned short s_h[SZ];
  __shared__ unsigned short s_l[SZ];

  const int tid = threadIdx.x;
  const int n     = (SPLITY == 1) ? blockIdx.x : blockIdx.x / SPLITY;
  const int split = (SPLITY == 1) ? 0 : blockIdx.x % SPLITY;
  const int y0 = split * OHB;
  const int r0 = y0 * STRIDE - 1;

  // zero both planes (halo + K-pad rows must be finite-zero)
  for (int i = tid * 8; i < SZ; i += 2048) {
    *(int4*)&s_h[i] = int4{0, 0, 0, 0};
    *(int4*)&s_l[i] = int4{0, 0, 0, 0};
  }
  __syncthreads();

  // stage NCHW fp32 -> NHWC bf16 hi/lo (rows clipped at runtime)
  constexpr int ROWF4 = IW / 4;
  for (int i = tid; i < IC * PH * ROWF4; i += 256) {
    int rw  = i % ROWF4;
    int t   = i / ROWF4;
    int row = t % PH;
    int ic  = t / PH;
    int giy = r0 + row;
    if (giy >= 0 && giy < IH) {
      float4 v = *(const float4*)(in + ((size_t)(n * IC + ic) * IH + giy) * IW + rw * 4);
      int base = (row * PW + rw * 4 + 1) * ICP + ic;
      float vv[4] = {v.x, v.y, v.z, v.w};
      #pragma unroll
      for (int e = 0; e < 4; ++e) {
        unsigned short h = f2bf(vv[e]);
        s_h[base + e * ICP] = h;
        s_l[base + e * ICP] = f2bf(vv[e] - bf2f(h));
      }
    }
  }
  __syncthreads();

  const int wave = tid >> 6;
  const int lane = tid & 63;
  const int l16  = lane & 15;
  const int quad = lane >> 4;

  f32x4 acc[MT][NTW];
  #pragma unroll
  for (int mt = 0; mt < MT; ++mt)
    #pragma unroll
    for (int nt = 0; nt < NTW; ++nt) acc[mt][nt] = f32x4{0.f, 0.f, 0.f, 0.f};

  for (int g = 0; g < KG; ++g) {
    // per-lane k decomposition (IC pow2 -> shifts; tap<=9)
    const int k0 = 32 * g + 8 * quad;
    const int tap = k0 / IC;
    const int ic0 = k0 % IC;
    const int ky = tap / 3;
    const int kx = tap - ky * 3;
    bf16x8 afh[MT], afl[MT];
    #pragma unroll
    for (int mt = 0; mt < MT; ++mt) {
      size_t wo = ((size_t)(mt * KG + g) * 64 + lane) * 8;
      afh[mt] = __builtin_bit_cast(bf16x8, *(const int4*)(Ah + wo));
      afl[mt] = __builtin_bit_cast(bf16x8, *(const int4*)(Al + wo));
    }
    #pragma unroll
    for (int nt = 0; nt < NTW; ++nt) {
      int p = (wave * NTW + nt) * 16 + l16;
      int py = p / OW, px = p % OW;
      int addr = ((py * STRIDE + ky) * PW + px * STRIDE + kx) * ICP + ic0;
      bf16x8 bh = __builtin_bit_cast(bf16x8, *(const int4*)&s_h[addr]);
      bf16x8 bl = __builtin_bit_cast(bf16x8, *(const int4*)&s_l[addr]);
      #pragma unroll
      for (int mt = 0; mt < MT; ++mt) {
        acc[mt][nt] = __builtin_amdgcn_mfma_f32_16x16x32_bf16(afh[mt], bh, acc[mt][nt], 0, 0, 0);
        acc[mt][nt] = __builtin_amdgcn_mfma_f32_16x16x32_bf16(afh[mt], bl, acc[mt][nt], 0, 0, 0);
        acc[mt][nt] = __builtin_amdgcn_mfma_f32_16x16x32_bf16(afl[mt], bh, acc[mt][nt], 0, 0, 0);
      }
    }
  }

  // epilogue: bias + relu, NCHW store (col=pos coalesced per oc-row)
  #pragma unroll
  for (int mt = 0; mt < MT; ++mt)
    #pragma unroll
    for (int nt = 0; nt < NTW; ++nt) {
      int p = (wave * NTW + nt) * 16 + l16;
      int py = p / OW, px = p % OW;
      #pragma unroll
      for (int r = 0; r < 4; ++r) {
        int oc = mt * 16 + quad * 4 + r;
        float v = acc[mt][nt][r] + bias[oc];
        out[((size_t)(n * OC + oc) * OH + y0 + py) * OW + px] = fmaxf(v, 0.f);
      }
    }
}

// ---------------- bf16 hi/lo split prepass (GEMM inputs) ----------------
__global__ __launch_bounds__(256) void split_a(
    const float* __restrict__ feats, unsigned short* __restrict__ ah,
    unsigned short* __restrict__ al)
{
  int i4 = blockIdx.x * 256 + threadIdx.x;
  int e = i4 * 4;
  int n = e >> 12;
  int k = e & 4095;
  int r = (n & 63) * 16 + (n >> 6);
  float4 v = ((const float4*)feats)[i4];
  ushort4 h, l;
  h.x = f2bf(v.x); l.x = f2bf(v.x - bf2f(h.x));
  h.y = f2bf(v.y); l.y = f2bf(v.y - bf2f(h.y));
  h.z = f2bf(v.z); l.z = f2bf(v.z - bf2f(h.z));
  h.w = f2bf(v.w); l.w = f2bf(v.w - bf2f(h.w));
  *(ushort4*)(ah + (size_t)r * 4096 + k) = h;
  *(ushort4*)(al + (size_t)r * 4096 + k) = l;
}

__global__ __launch_bounds__(256) void split_b(
    const float* __restrict__ w_ih, unsigned short* __restrict__ bh,
    unsigned short* __restrict__ bl)
{
  int i4 = blockIdx.x * 256 + threadIdx.x;
  float4 v = ((const float4*)w_ih)[i4];
  ushort4 h, l;
  h.x = f2bf(v.x); l.x = f2bf(v.x - bf2f(h.x));
  h.y = f2bf(v.y); l.y = f2bf(v.y - bf2f(h.y));
  h.z = f2bf(v.z); l.z = f2bf(v.z - bf2f(h.z));
  h.w = f2bf(v.w); l.w = f2bf(v.w - bf2f(h.w));
  ((ushort4*)bh)[i4] = h;
  ((ushort4*)bl)[i4] = l;
}

// ---------------- Xg partials: bf16 split-MFMA GEMM ----------------
__global__ __launch_bounds__(256) void mfma_xg(
    const unsigned short* __restrict__ Ah, const unsigned short* __restrict__ Al,
    const unsigned short* __restrict__ Bh, const unsigned short* __restrict__ Bl,
    float* __restrict__ part)
{
  __shared__ unsigned short s_ah[128 * 40];
  __shared__ unsigned short s_al[128 * 40];
  __shared__ unsigned short s_bh[128 * 40];
  __shared__ unsigned short s_bl[128 * 40];

  const int tid = threadIdx.x;
  const int col0 = blockIdx.x * 128;
  const int row0 = blockIdx.y * 128;
  const int kbase = blockIdx.z * 512;
  float* outp = part + (size_t)blockIdx.z * 1048576;

  const int wave = tid >> 6;
  const int lane = tid & 63;
  const int wr = wave >> 1, wc = wave & 1;
  const int quad = lane >> 4;
  const int l16 = lane & 15;

  f32x4 acc[4][4];
  #pragma unroll
  for (int i = 0; i < 4; ++i)
    #pragma unroll
    for (int j = 0; j < 4; ++j) acc[i][j] = f32x4{0.f, 0.f, 0.f, 0.f};

  for (int step = 0; step < 16; ++step) {
    const int koff = kbase + step * 32;
    #pragma unroll
    for (int c = tid; c < 512; c += 256) {
      int row = c >> 2, kc = (c & 3) * 8;
      int4 va = *(const int4*)(Ah + (size_t)(row0 + row) * 4096 + koff + kc);
      int4 vb = *(const int4*)(Al + (size_t)(row0 + row) * 4096 + koff + kc);
      int4 vc = *(const int4*)(Bh + (size_t)(col0 + row) * 4096 + koff + kc);
      int4 vd = *(const int4*)(Bl + (size_t)(col0 + row) * 4096 + koff + kc);
      *(int4*)&s_ah[row * 40 + kc] = va;
      *(int4*)&s_al[row * 40 + kc] = vb;
      *(int4*)&s_bh[row * 40 + kc] = vc;
      *(int4*)&s_bl[row * 40 + kc] = vd;
    }
    __syncthreads();

    bf16x8 arh[4], arl[4];
    #pragma unroll
    for (int i = 0; i < 4; ++i) {
      int m = wr * 64 + i * 16 + l16;
      arh[i] = __builtin_bit_cast(bf16x8, *(const int4*)&s_ah[m * 40 + quad * 8]);
      arl[i] = __builtin_bit_cast(bf16x8, *(const int4*)&s_al[m * 40 + quad * 8]);
    }
    #pragma unroll
    for (int j = 0; j < 4; ++j) {
      int nn = wc * 64 + j * 16 + l16;
      bf16x8 brh = __builtin_bit_cast(bf16x8, *(const int4*)&s_bh[nn * 40 + quad * 8]);
      bf16x8 brl = __builtin_bit_cast(bf16x8, *(const int4*)&s_bl[nn * 40 + quad * 8]);
      #pragma unroll
      for (int i = 0; i < 4; ++i) {
        acc[i][j] = __builtin_amdgcn_mfma_f32_16x16x32_bf16(arh[i], brh, acc[i][j], 0, 0, 0);
        acc[i][j] = __builtin_amdgcn_mfma_f32_16x16x32_bf16(arh[i], brl, acc[i][j], 0, 0, 0);
        acc[i][j] = __builtin_amdgcn_mfma_f32_16x16x32_bf16(arl[i], brh, acc[i][j], 0, 0, 0);
      }
    }
    __syncthreads();
  }

  #pragma unroll
  for (int i = 0; i < 4; ++i)
    #pragma unroll
    for (int j = 0; j < 4; ++j) {
      int row = row0 + wr * 64 + i * 16 + quad * 4;
      int col = col0 + wc * 64 + j * 16 + l16;
      #pragma unroll
      for (int r = 0; r < 4; ++r)
        outp[(size_t)(row + r) * 1024 + col] = acc[i][j][r];
    }
}

// xg = sum_z p[z] + (b_ih + b_hh)
__global__ __launch_bounds__(256) void reduce_xg(
    const float* __restrict__ p, const float* __restrict__ b_ih,
    const float* __restrict__ b_hh, float* __restrict__ xg)
{
  int i = blockIdx.x * 256 + threadIdx.x;
  float4 s = {0.f, 0.f, 0.f, 0.f};
  #pragma unroll
  for (int z = 0; z < 8; ++z) {
    float4 a = ((const float4*)p)[(size_t)z * 262144 + i];
    s.x += a.x; s.y += a.y; s.z += a.z; s.w += a.w;
  }
  int cb = i & 255;
  float4 bi = ((const float4*)b_ih)[cb];
  float4 bh = ((const float4*)b_hh)[cb];
  float4 o;
  o.x = s.x + bi.x + bh.x;
  o.y = s.y + bi.y + bh.y;
  o.z = s.z + bi.z + bh.z;
  o.w = s.w + bi.w + bh.w;
  ((float4*)xg)[i] = o;
}

// ---------------- persistent LSTM recurrence ----------------
// R19 = R14/R18 skeleton (128 blocks = 16 b x 8 j-chunks of 32, tid=r*8+q,
// 1 poller/word, 2 barriers/step, owner-lane activations, single-tanh
// combine) + TRUE issue/wait split for the per-step weight stream:
//  1) raw asm global_load_dwordx4 x8 (no waitcnt -> in flight)
//  2) poll h(s-1) (its atomic-load vmcnt(0) waits co-drain ours: safe,
//     and the compiler's own counted waits only OVERcount -> safe)
//  3) explicit s_waitcnt vmcnt(0) + sched_barrier(0) (rule #18) -> matvec.
// R18 proved the "+v" pre-poll pin drains BEFORE the poll (serial, 94.5us);
// this overlaps the 0.85us drain with the 0.5us poll. waves_per_eu(4,4):
// budget 128 VGPR so the 32 asm-held regs survive the poll (1 block/CU
// anyway at 128 blocks). Both branches drain before loop-bottom (no WAW).
__global__ __launch_bounds__(1024)
__attribute__((amdgpu_waves_per_eu(4, 4)))
void lstm_kernel(
    const float* __restrict__ xg, const float* __restrict__ w_hh,
    float* __restrict__ hs, unsigned long long* __restrict__ hpair)
{
  const int b = blockIdx.x & 15;
  const int c = blockIdx.x >> 4;        // j-chunk 0..7
  const int tid = threadIdx.x;
  const int r = tid >> 3;               // 0..127 = gate*32 + jl
  const int q = tid & 7;                // K-eighth
  const int gate = r >> 5;              // wave-uniform
  const int jl = r & 31;
  const int j = c * 32 + jl;            // global column 0..255

  const f32x4* wrow = (const f32x4*)(w_hh + ((size_t)(gate * 256 + j)) * 256 + q * 32);

  __shared__ float s_h2[8][36];          // [q][k], +4 pad -> distinct bank-quads
  __shared__ float s_gates[4][33];       // [gate][jl], ACTIVATED values
  float c_reg = 0.f;

  for (int s = 0; s < 64; ++s) {
    // 1) issue the 8 weight loads raw (async, stay in flight through poll)
    f32x4 wv[8];
    #pragma unroll
    for (int k = 0; k < 8; ++k)
      asm volatile("global_load_dwordx4 %0, %1, off"
                   : "=v"(wv[k]) : "v"(wrow + k));

    // 2) xg prefetch (independent of h)
    float xv = 0.f;
    if (q == 0) xv = xg[(size_t)(s * 16 + b) * 1024 + gate * 256 + j];

    float gv = 0.f;
    if (s > 0) {
      // 3) poll h(s-1): tid<256, 1 poller/word (weights drain underneath)
      if (tid < 256) {
        const unsigned long long* src = hpair + ((size_t)(s - 1) * 16 + b) * 256 + tid;
        unsigned long long pv;
        do {
          pv = __hip_atomic_load(src, __ATOMIC_RELAXED, __HIP_MEMORY_SCOPE_AGENT);
        } while ((unsigned int)(pv >> 32) != (unsigned int)s);
        s_h2[tid >> 5][tid & 31] = __uint_as_float((unsigned int)pv);
      }
      __syncthreads();
      // 4) wait for weight loads, fence scheduling, then matvec
      asm volatile("s_waitcnt vmcnt(0)" ::: "memory");
      __builtin_amdgcn_sched_barrier(0);
      const float4* hp = (const float4*)&s_h2[q][0];
      float p = 0.f;
      #pragma unroll
      for (int k = 0; k < 8; ++k) {
        float4 h4 = hp[k];
        p = fmaf(h4.x, wv[k][0], p);
        p = fmaf(h4.y, wv[k][1], p);
        p = fmaf(h4.z, wv[k][2], p);
        p = fmaf(h4.w, wv[k][3], p);
      }
      p += __shfl_xor(p, 1);
      p += __shfl_xor(p, 2);
      p += __shfl_xor(p, 4);
      gv = p;
    } else {
      __syncthreads();   // uniform barrier count
      asm volatile("s_waitcnt vmcnt(0)" ::: "memory");  // drain before re-issue
    }
    // 5) owner-lane activation (gate wave-uniform -> branchless per wave)
    if (q == 0) {
      float pre = gv + xv;
      s_gates[gate][jl] = (gate == 2) ? ftanh_(pre) : fsig_(pre);
    }
    __syncthreads();
    // 6) combine: one tanh on the serial chain
    if (tid < 32) {
      float si = s_gates[0][tid], sf = s_gates[1][tid];
      float tg = s_gates[2][tid], so = s_gates[3][tid];
      float cn = sf * c_reg + si * tg;
      c_reg = cn;
      float hv = so * ftanh_(cn);
      hs[(size_t)s * 4096 + b * 256 + c * 32 + tid] = hv;
      unsigned long long pv =
          ((unsigned long long)(unsigned int)(s + 1) << 32) | __float_as_uint(hv);
      __hip_atomic_store(hpair + ((size_t)s * 16 + b) * 256 + c * 32 + tid, pv,
                         __ATOMIC_RELAXED, __HIP_MEMORY_SCOPE_AGENT);
    }
  }
}

// ---------------- classifier head ----------------
__global__ __launch_bounds__(64) void cls_kernel(
    const float* __restrict__ hs, const float* __restrict__ cw,
    const float* __restrict__ cb, float* __restrict__ out)
{
  const int id = blockIdx.x;
  const int b = id / 53;
  const int t = id % 53;
  const int s = 11 + t;
  const int lane = threadIdx.x;
  float4 hv = ((const float4*)(hs + (size_t)s * 4096 + b * 256))[lane];
  float4 wv = ((const float4*)cw)[lane];
  float p = hv.x * wv.x + hv.y * wv.y + hv.z * wv.z + hv.w * wv.w;
  #pragma unroll
  for (int off = 32; off >= 1; off >>= 1) p += __shfl_xor(p, off);
  if (lane == 0) out[id] = tanhf(p + cb[0]);
}

// ---------------------------------------------------------------------------
extern "C" void kernel_launch(void* const* d_in, const int* in_sizes, int n_in,
                              void* d_out, int out_size, void* d_ws, size_t ws_size,
                              hipStream_t stream)
{
  (void)in_sizes; (void)n_in; (void)out_size; (void)ws_size;
  const float* imgs = (const float*)d_in[0];
  const float* w_ih  = (const float*)d_in[31];
  const float* w_hh  = (const float*)d_in[32];
  const float* b_ih  = (const float*)d_in[33];
  const float* b_hh  = (const float*)d_in[34];
  const float* cls_w = (const float*)d_in[35];
  const float* cls_b = (const float*)d_in[36];
  float* out = (float*)d_out;

  float* ws   = (float*)d_ws;
  float* actA = ws;
  float* actB = actA + 16777216;
  float* xg   = actB + 16777216;
  float* hs   = xg + 1048576;
  unsigned long long* hpair = (unsigned long long*)(hs + 262144);
  float* wfp  = hs + 262144 + 524288;
  static const int ocs[6] = {16, 16, 32, 32, 64, 64};
  static const int ics[6] = {3, 16, 16, 32, 32, 64};
  float* wf[6];
  size_t off = 0;
  for (int i = 0; i < 6; ++i) { wf[i] = wfp + off; off += (size_t)ocs[i] * ics[i] * 12; }
  float* biasp = wfp + off;
  float* bias[6];
  for (int i = 0; i < 6; ++i) bias[i] = biasp + i * 64;

  // packed MFMA weights (L1..L5): sizes MT*KG*512 ushorts per plane
  static const int psz[5] = {2560, 5120, 9216, 18432, 36864};
  unsigned short* WH = (unsigned short*)(biasp + 6 * 64);
  unsigned short* WL = WH + 72192;
  unsigned short *wh[5], *wl[5];
  {
    int o = 0;
    for (int i = 0; i < 5; ++i) { wh[i] = WH + o; wl[i] = WL + o; o += psz[i]; }
  }

  float* partials = actA;       // reused post-conv
  unsigned short* Ah = (unsigned short*)(actA + 8388608);
  unsigned short* Al = Ah + 4194304;
  unsigned short* Bh = Al + 4194304;
  unsigned short* Bl = Bh + 4194304;

  FoldPack fp;
  for (int i = 0; i < 6; ++i) {
    fp.w[i] = (const float*)d_in[1 + 5*i];
    fp.g[i] = (const float*)d_in[2 + 5*i];
    fp.b[i] = (const float*)d_in[3 + 5*i];
    fp.m[i] = (const float*)d_in[4 + 5*i];
    fp.v[i] = (const float*)d_in[5 + 5*i];
    fp.wf[i] = wf[i];
    fp.bias[i] = bias[i];
    fp.oc[i] = ocs[i];
    fp.ic[i] = ics[i];
  }
  fold_all<<<dim3(8, 6), 256, 0, stream>>>(fp);

  PackPack pp;
  static const int kgs[5] = {5, 5, 9, 9, 18};
  static const int krs[5] = {144, 144, 288, 288, 576};
  for (int i = 0; i < 5; ++i) {
    pp.w[i] = (const float*)d_in[1 + 5*(i+1)];
    pp.g[i] = (const float*)d_in[2 + 5*(i+1)];
    pp.v[i] = (const float*)d_in[5 + 5*(i+1)];
    pp.wh[i] = wh[i];
    pp.wl[i] = wl[i];
    pp.ic[i] = ics[i+1];
    pp.oc[i] = ocs[i+1];
    pp.kg[i] = kgs[i];
    pp.kreal[i] = krs[i];
  }
  pack_w<<<dim3(36, 5), 256, 0, stream>>>(pp);

  // L0 fp32 direct conv
  conv_bn_relu<3, 16, 64, 64, 2, 4, 2, 1, 4><<<2048, 256, 0, stream>>>(imgs, wf[0], bias[0], actA);
  //            IC  OC  IH  IW  S SPL KG ZR
  conv_mfma<16, 16, 32, 32, 1, 4, 5, 1><<<4096, 256, 0, stream>>>(actA, wh[0], wl[0], bias[1], actB);
  conv_mfma<16, 32, 32, 32, 2, 4, 5, 1><<<4096, 256, 0, stream>>>(actB, wh[1], wl[1], bias[2], actA);
  conv_mfma<32, 32, 16, 16, 1, 1, 9, 0><<<1024, 256, 0, stream>>>(actA, wh[2], wl[2], bias[3], actB);
  conv_mfma<32, 64, 16, 16, 2, 1, 9, 0><<<1024, 256, 0, stream>>>(actB, wh[3], wl[3], bias[4], actA);
  conv_mfma<64, 64,  8,  8, 1, 1, 18, 0><<<1024, 256, 0, stream>>>(actA, wh[4], wl[4], bias[5], actB);

  split_a<<<4096, 256, 0, stream>>>(actB, Ah, Al);
  split_b<<<4096, 256, 0, stream>>>(w_ih, Bh, Bl);
  mfma_xg<<<dim3(8, 8, 8), 256, 0, stream>>>(Ah, Al, Bh, Bl, partials);
  reduce_xg<<<1024, 256, 0, stream>>>(partials, b_ih, b_hh, xg);
  lstm_kernel<<<128, 1024, 0, stream>>>(xg, w_hh, hs, hpair);
  cls_kernel<<<848, 64, 0, stream>>>(hs, cls_w, cls_b, out);
}

// Round 11
// 465.523 us; speedup vs baseline: 1.3779x; 1.3779x over previous
//
#include <hip/hip_runtime.h>
#include <cmath>

// ---------------------------------------------------------------------------
// 6x (conv3x3+BN+ReLU) -> LSTM(4096->256) over S=64 -> tanh(linear).
// R9: convs L1..L5 ported to split-bf16 MFMA implicit-GEMM (hh+hl+lh, proven
// absmax 3e-8). L0 (K=27) stays fp32.
// LSTM ledger (measured, CLOSED at ~94us):
//  R14/R18 94-94.5us best (128 blk x 1024 thr, 8 pollers/word, 2 barriers).
//  R12 356us all-to-all / R16 111us LDS weights / R17 124us 16-pollers /
//  R19 267us raw-asm async loads: vmcnt is IN-ORDER -- a wave's poll waits
//   queue behind its own in-flight loads, so in-wave issue/wait overlap is
//   impossible; and the 12 non-polling waves already overlap their weight
//   loads with the poll naturally. The ~1.45us/step floor is LLC visibility
//   round-trip + 2 barriers + serial combine, weight stream mostly hidden.
// R20: lstm reverted to exact R18 (best). New: split_a FUSED into conv L5's
// epilogue -- L5 now writes the bf16 hi/lo planes (Ah/Al) directly in
// split_a's layout (r=(n&63)*16+(n>>6), k=oc*64+pos; identical f2bf math ->
// bit-identical), deleting the 33.6MB re-layout pass + one launch (~7us).
// ---------------------------------------------------------------------------

typedef __attribute__((ext_vector_type(8))) __bf16 bf16x8;
typedef __attribute__((ext_vector_type(4))) float f32x4;

__device__ __forceinline__ float sigmoidf_(float x) { return 1.f / (1.f + expf(-x)); }

__device__ __forceinline__ float fsig_(float x) {
  return __builtin_amdgcn_rcpf(1.f + __expf(-x));
}
__device__ __forceinline__ float ftanh_(float x) {
  float xc = fminf(fmaxf(x, -15.f), 15.f);
  float e = __expf(2.f * xc);
  return (e - 1.f) * __builtin_amdgcn_rcpf(e + 1.f);
}

__device__ __forceinline__ unsigned short f2bf(float f) {   // RNE
  unsigned u = __float_as_uint(f);
  unsigned r = (u + 0x7fffu + ((u >> 16) & 1u)) >> 16;
  return (unsigned short)r;
}
__device__ __forceinline__ float bf2f(unsigned short h) {
  return __uint_as_float(((unsigned)h) << 16);
}

// ---------------- fold BN into conv weights (fp32 path + bias) ----------
struct FoldPack {
  const float *w[6], *g[6], *b[6], *m[6], *v[6];
  float *wf[6], *bias[6];
  int oc[6], ic[6];
};

__global__ __launch_bounds__(256) void fold_all(FoldPack p) {
  const int layer = blockIdx.y;
  const int OC = p.oc[layer], IC = p.ic[layer];
  const int total = OC * IC * 9;
  const float* w = p.w[layer];
  float* wf = p.wf[layer];
  for (int i = blockIdx.x * 256 + threadIdx.x; i < total; i += gridDim.x * 256) {
    int oc = i / (IC * 9);
    int r  = i % (IC * 9);
    int ic = r / 9;
    int k  = r % 9;
    int ky = k / 3, kx = k % 3;
    float inv = p.g[layer][oc] / sqrtf(p.v[layer][oc] + 1e-5f);
    wf[(((ic * 3 + ky) * OC) + oc) * 4 + kx] = w[i] * inv;
  }
  if (blockIdx.x == 0) {
    int i = threadIdx.x;
    if (i < OC) {
      float inv = p.g[layer][i] / sqrtf(p.v[layer][i] + 1e-5f);
      p.bias[layer][i] = p.b[layer][i] - p.m[layer][i] * inv;
    }
  }
}

// ---------------- pack BN-folded weights into MFMA A-frag layout ----------
// A[m=oc][k], k = tap*IC + ic (tap-major). Layout: [mt*KG+g][lane(64)][8]
// where lane -> (m = mt*16 + (lane&15), k = 32g + 8*(lane>>4) + j).
// k >= Kreal -> 0 (zero tap-9 padding for IC=16 layers). bf16 hi + lo.
struct PackPack {
  const float *w[5], *g[5], *v[5];
  unsigned short *wh[5], *wl[5];
  int ic[5], oc[5], kg[5], kreal[5];
};

__global__ __launch_bounds__(256) void pack_w(PackPack p) {
  const int layer = blockIdx.y;
  const int IC = p.ic[layer], KG = p.kg[layer], K = p.kreal[layer];
  const int MT = p.oc[layer] / 16;
  const int total = MT * KG * 512;
  for (int i = blockIdx.x * 256 + threadIdx.x; i < total; i += gridDim.x * 256) {
    int j = i & 7;
    int lane = (i >> 3) & 63;
    int gmt = i >> 9;               // = mt*KG + g
    int m = (gmt / KG) * 16 + (lane & 15);
    int k = 32 * (gmt % KG) + 8 * (lane >> 4) + j;
    float val = 0.f;
    if (k < K) {
      int tap = k / IC, ic = k % IC;
      int ky = tap / 3, kx = tap % 3;
      float inv = p.g[layer][m] / sqrtf(p.v[layer][m] + 1e-5f);
      val = p.w[layer][((m * IC + ic) * 3 + ky) * 3 + kx] * inv;
    }
    unsigned short h = f2bf(val);
    p.wh[layer][i] = h;
    p.wl[layer][i] = f2bf(val - bf2f(h));
  }
}

// ---------------- fp32 direct conv (L0 only: IC=3, K=27) ----------------
template<int IC, int OC, int IH, int IW, int STRIDE, int TPOS, int SPLITY,
         int ICS, int MINW>
__global__ __launch_bounds__(256, MINW) void conv_bn_relu(
    const float* __restrict__ in, const float* __restrict__ wf,
    const float* __restrict__ bias, float* __restrict__ out)
{
  constexpr int OH = IH / STRIDE, OW = IW / STRIDE;
  constexpr int OHB = OH / SPLITY;
  constexpr int RIH = (SPLITY == 1) ? (IH + 2) : ((OHB - 1) * STRIDE + 3);
  constexpr int PIW = IW + 4;
  constexpr int PLANE = RIH * PIW;
  constexpr int NPOS = OHB * OW;
  constexpr int WPOS = NPOS / TPOS;
  constexpr int SLOT = WPOS * ICS;
  constexpr int GROUPS = 256 / SLOT;
  constexpr int TOC = OC / GROUPS;
  constexpr int CH = IC / ICS;
  constexpr int SPAN = (TPOS - 1) * STRIDE + 3;
  constexpr int NW = (SPAN + 3) / 4;
  constexpr int XSLOTS = OW / TPOS;
  static_assert(SLOT % 64 == 0 && GROUPS * SLOT == 256 && GROUPS * TOC == OC, "tiling");

  __shared__ float s_in[IC * PLANE];

  const int tid = threadIdx.x;
  const int n     = (SPLITY == 1) ? blockIdx.x : blockIdx.x / SPLITY;
  const int split = (SPLITY == 1) ? 0 : blockIdx.x % SPLITY;
  const int ry0 = split * OHB;
  const int r0  = ry0 * STRIDE - 1;

  for (int i = tid; i < IC * PLANE / 4; i += 256)
    ((float4*)s_in)[i] = float4{0.f, 0.f, 0.f, 0.f};
  __syncthreads();

  constexpr int ROWF4 = IW / 4;
  constexpr int NSTG = IC * RIH * ROWF4;
  for (int i = tid; i < NSTG; i += 256) {
    int rw  = i % ROWF4;
    int t   = i / ROWF4;
    int row = t % RIH;
    int ic  = t / RIH;
    int giy = r0 + row;
    if (giy >= 0 && giy < IH) {
      float4 v = *(const float4*)(in + ((size_t)(n * IC + ic) * IH + giy) * IW + rw * 4);
      float* dst = &s_in[(ic * RIH + row) * PIW + 1 + rw * 4];
      dst[0] = v.x; dst[1] = v.y; dst[2] = v.z; dst[3] = v.w;
    }
  }
  __syncthreads();

  const int group  = tid / SLOT;
  const int sl     = tid % SLOT;
  const int icq    = sl / WPOS;
  const int worker = sl % WPOS;
  const int oy  = worker / XSLOTS;
  const int ox0 = (worker % XSLOTS) * TPOS;
  const int xb  = ox0 * STRIDE;

  const int oc0u = __builtin_amdgcn_readfirstlane(group * TOC);
  const float4* wg = (const float4*)wf + oc0u;

  float acc[TOC][TPOS];
  #pragma unroll
  for (int a = 0; a < TOC; ++a)
    #pragma unroll
    for (int p = 0; p < TPOS; ++p) acc[a][p] = 0.f;

  for (int icl = 0; icl < CH; ++icl) {
    const int ic = icq * CH + icl;
    const float* sI = &s_in[ic * PLANE];
    #pragma unroll
    for (int ky = 0; ky < 3; ++ky) {
      float row[NW * 4];
      {
        const float4* rp = (const float4*)&sI[(oy * STRIDE + ky) * PIW + xb];
        #pragma unroll
        for (int w = 0; w < NW; ++w) {
          float4 t4 = rp[w];
          row[4*w+0] = t4.x; row[4*w+1] = t4.y;
          row[4*w+2] = t4.z; row[4*w+3] = t4.w;
        }
      }
      const float4* wrow = wg + (ic * 3 + ky) * OC;
      #pragma unroll
      for (int oc = 0; oc < TOC; ++oc) {
        float4 w4 = wrow[oc];
        #pragma unroll
        for (int p = 0; p < TPOS; ++p)
          acc[oc][p] = fmaf(row[p * STRIDE + 0], w4.x,
                       fmaf(row[p * STRIDE + 1], w4.y,
                       fmaf(row[p * STRIDE + 2], w4.z, acc[oc][p])));
      }
    }
  }

  #pragma unroll
  for (int d = WPOS; d < SLOT; d <<= 1)
    #pragma unroll
    for (int oc = 0; oc < TOC; ++oc)
      #pragma unroll
      for (int p = 0; p < TPOS; ++p)
        acc[oc][p] += __shfl_xor(acc[oc][p], d);

  if (icq == 0) {
    float* outN = out + (size_t)n * (OC * OH * OW);
    #pragma unroll
    for (int oc = 0; oc < TOC; ++oc) {
      const float bb = bias[oc0u + oc];
      float* op = outN + ((size_t)(oc0u + oc) * OH + (ry0 + oy)) * OW + ox0;
      #pragma unroll
      for (int vq = 0; vq < TPOS / 4; ++vq) {
        float4 val;
        val.x = fmaxf(acc[oc][vq*4+0] + bb, 0.f);
        val.y = fmaxf(acc[oc][vq*4+1] + bb, 0.f);
        val.z = fmaxf(acc[oc][vq*4+2] + bb, 0.f);
        val.w = fmaxf(acc[oc][vq*4+3] + bb, 0.f);
        *(float4*)(op + vq * 4) = val;
      }
    }
  }
}

// ---------------- MFMA implicit-GEMM conv (L1..L5) ----------------
// M=OC (A=packed weights, global), N=positions (B=input, LDS NHWC bf16 h/l),
// K=IC*9 (padded to KG*32). C row=oc (quad*4+reg), col=pos (lane&15).
// OSPLIT=1 (L5): epilogue writes bf16 hi/lo planes in split_a's layout
// (r=(n&63)*16+(n>>6), k=oc*64+pos) instead of fp32 NCHW -- fuses split_a.
template<int IC, int OC, int IH, int IW, int STRIDE, int SPLITY, int KG,
         int ZROW, int OSPLIT>
__global__ __launch_bounds__(256, 2) void conv_mfma(
    const float* __restrict__ in, const unsigned short* __restrict__ Ah,
    const unsigned short* __restrict__ Al, const float* __restrict__ bias,
    float* __restrict__ out, unsigned short* __restrict__ oah,
    unsigned short* __restrict__ oal)
{
  constexpr int OH = IH / STRIDE, OW = IW / STRIDE;
  constexpr int OHB = OH / SPLITY;
  constexpr int N = OHB * OW;
  constexpr int NT = N / 16;
  constexpr int NTW = NT / 4;              // n-tiles per wave
  constexpr int MT = OC / 16;
  constexpr int ICP = IC + 8;              // bank-skew pad (2-way worst, stride1)
  constexpr int PW = IW + 3;
  constexpr int PH = (OHB - 1) * STRIDE + 3 + ZROW;
  constexpr int SZ = ((PH * PW * ICP + 7) / 8) * 8;
  static_assert(NT % 4 == 0, "nt");
  static_assert(!OSPLIT || SPLITY == 1, "osplit needs full plane");

  __shared__ unsigned short s_h[SZ];
  __shared__ unsigned short s_l[SZ];

  const int tid = threadIdx.x;
  const int n     = (SPLITY == 1) ? blockIdx.x : blockIdx.x / SPLITY;
  const int split = (SPLITY == 1) ? 0 : blockIdx.x % SPLITY;
  const int y0 = split * OHB;
  const int r0 = y0 * STRIDE - 1;

  // zero both planes (halo + K-pad rows must be finite-zero)
  for (int i = tid * 8; i < SZ; i += 2048) {
    *(int4*)&s_h[i] = int4{0, 0, 0, 0};
    *(int4*)&s_l[i] = int4{0, 0, 0, 0};
  }
  __syncthreads();

  // stage NCHW fp32 -> NHWC bf16 hi/lo (rows clipped at runtime)
  constexpr int ROWF4 = IW / 4;
  for (int i = tid; i < IC * PH * ROWF4; i += 256) {
    int rw  = i % ROWF4;
    int t   = i / ROWF4;
    int row = t % PH;
    int ic  = t / PH;
    int giy = r0 + row;
    if (giy >= 0 && giy < IH) {
      float4 v = *(const float4*)(in + ((size_t)(n * IC + ic) * IH + giy) * IW + rw * 4);
      int base = (row * PW + rw * 4 + 1) * ICP + ic;
      float vv[4] = {v.x, v.y, v.z, v.w};
      #pragma unroll
      for (int e = 0; e < 4; ++e) {
        unsigned short h = f2bf(vv[e]);
        s_h[base + e * ICP] = h;
        s_l[base + e * ICP] = f2bf(vv[e] - bf2f(h));
      }
    }
  }
  __syncthreads();

  const int wave = tid >> 6;
  const int lane = tid & 63;
  const int l16  = lane & 15;
  const int quad = lane >> 4;

  f32x4 acc[MT][NTW];
  #pragma unroll
  for (int mt = 0; mt < MT; ++mt)
    #pragma unroll
    for (int nt = 0; nt < NTW; ++nt) acc[mt][nt] = f32x4{0.f, 0.f, 0.f, 0.f};

  for (int g = 0; g < KG; ++g) {
    // per-lane k decomposition (IC pow2 -> shifts; tap<=9)
    const int k0 = 32 * g + 8 * quad;
    const int tap = k0 / IC;
    const int ic0 = k0 % IC;
    const int ky = tap / 3;
    const int kx = tap - ky * 3;
    bf16x8 afh[MT], afl[MT];
    #pragma unroll
    for (int mt = 0; mt < MT; ++mt) {
      size_t wo = ((size_t)(mt * KG + g) * 64 + lane) * 8;
      afh[mt] = __builtin_bit_cast(bf16x8, *(const int4*)(Ah + wo));
      afl[mt] = __builtin_bit_cast(bf16x8, *(const int4*)(Al + wo));
    }
    #pragma unroll
    for (int nt = 0; nt < NTW; ++nt) {
      int p = (wave * NTW + nt) * 16 + l16;
      int py = p / OW, px = p % OW;
      int addr = ((py * STRIDE + ky) * PW + px * STRIDE + kx) * ICP + ic0;
      bf16x8 bh = __builtin_bit_cast(bf16x8, *(const int4*)&s_h[addr]);
      bf16x8 bl = __builtin_bit_cast(bf16x8, *(const int4*)&s_l[addr]);
      #pragma unroll
      for (int mt = 0; mt < MT; ++mt) {
        acc[mt][nt] = __builtin_amdgcn_mfma_f32_16x16x32_bf16(afh[mt], bh, acc[mt][nt], 0, 0, 0);
        acc[mt][nt] = __builtin_amdgcn_mfma_f32_16x16x32_bf16(afh[mt], bl, acc[mt][nt], 0, 0, 0);
        acc[mt][nt] = __builtin_amdgcn_mfma_f32_16x16x32_bf16(afl[mt], bh, acc[mt][nt], 0, 0, 0);
      }
    }
  }

  if constexpr (OSPLIT) {
    // epilogue: bias+relu, write bf16 hi/lo split planes (split_a layout)
    const int rn = (n & 63) * 16 + (n >> 6);
    unsigned short* pah = oah + (size_t)rn * 4096;
    unsigned short* pal = oal + (size_t)rn * 4096;
    #pragma unroll
    for (int mt = 0; mt < MT; ++mt)
      #pragma unroll
      for (int nt = 0; nt < NTW; ++nt) {
        int p = (wave * NTW + nt) * 16 + l16;    // pos 0..63 (SPLITY==1)
        #pragma unroll
        for (int r = 0; r < 4; ++r) {
          int oc = mt * 16 + quad * 4 + r;
          float v = fmaxf(acc[mt][nt][r] + bias[oc], 0.f);
          unsigned short h = f2bf(v);
          pah[oc * 64 + p] = h;
          pal[oc * 64 + p] = f2bf(v - bf2f(h));
        }
      }
  } else {
    // epilogue: bias + relu, NCHW store (col=pos coalesced per oc-row)
    #pragma unroll
    for (int mt = 0; mt < MT; ++mt)
      #pragma unroll
      for (int nt = 0; nt < NTW; ++nt) {
        int p = (wave * NTW + nt) * 16 + l16;
        int py = p / OW, px = p % OW;
        #pragma unroll
        for (int r = 0; r < 4; ++r) {
          int oc = mt * 16 + quad * 4 + r;
          float v = acc[mt][nt][r] + bias[oc];
          out[((size_t)(n * OC + oc) * OH + y0 + py) * OW + px] = fmaxf(v, 0.f);
        }
      }
  }
}

// ---------------- bf16 hi/lo split prepass (w_ih only) ----------------
__global__ __launch_bounds__(256) void split_b(
    const float* __restrict__ w_ih, unsigned short* __restrict__ bh,
    unsigned short* __restrict__ bl)
{
  int i4 = blockIdx.x * 256 + threadIdx.x;
  float4 v = ((const float4*)w_ih)[i4];
  ushort4 h, l;
  h.x = f2bf(v.x); l.x = f2bf(v.x - bf2f(h.x));
  h.y = f2bf(v.y); l.y = f2bf(v.y - bf2f(h.y));
  h.z = f2bf(v.z); l.z = f2bf(v.z - bf2f(h.z));
  h.w = f2bf(v.w); l.w = f2bf(v.w - bf2f(h.w));
  ((ushort4*)bh)[i4] = h;
  ((ushort4*)bl)[i4] = l;
}

// ---------------- Xg partials: bf16 split-MFMA GEMM ----------------
__global__ __launch_bounds__(256) void mfma_xg(
    const unsigned short* __restrict__ Ah, const unsigned short* __restrict__ Al,
    const unsigned short* __restrict__ Bh, const unsigned short* __restrict__ Bl,
    float* __restrict__ part)
{
  __shared__ unsigned short s_ah[128 * 40];
  __shared__ unsigned short s_al[128 * 40];
  __shared__ unsigned short s_bh[128 * 40];
  __shared__ unsigned short s_bl[128 * 40];

  const int tid = threadIdx.x;
  const int col0 = blockIdx.x * 128;
  const int row0 = blockIdx.y * 128;
  const int kbase = blockIdx.z * 512;
  float* outp = part + (size_t)blockIdx.z * 1048576;

  const int wave = tid >> 6;
  const int lane = tid & 63;
  const int wr = wave >> 1, wc = wave & 1;
  const int quad = lane >> 4;
  const int l16 = lane & 15;

  f32x4 acc[4][4];
  #pragma unroll
  for (int i = 0; i < 4; ++i)
    #pragma unroll
    for (int j = 0; j < 4; ++j) acc[i][j] = f32x4{0.f, 0.f, 0.f, 0.f};

  for (int step = 0; step < 16; ++step) {
    const int koff = kbase + step * 32;
    #pragma unroll
    for (int c = tid; c < 512; c += 256) {
      int row = c >> 2, kc = (c & 3) * 8;
      int4 va = *(const int4*)(Ah + (size_t)(row0 + row) * 4096 + koff + kc);
      int4 vb = *(const int4*)(Al + (size_t)(row0 + row) * 4096 + koff + kc);
      int4 vc = *(const int4*)(Bh + (size_t)(col0 + row) * 4096 + koff + kc);
      int4 vd = *(const int4*)(Bl + (size_t)(col0 + row) * 4096 + koff + kc);
      *(int4*)&s_ah[row * 40 + kc] = va;
      *(int4*)&s_al[row * 40 + kc] = vb;
      *(int4*)&s_bh[row * 40 + kc] = vc;
      *(int4*)&s_bl[row * 40 + kc] = vd;
    }
    __syncthreads();

    bf16x8 arh[4], arl[4];
    #pragma unroll
    for (int i = 0; i < 4; ++i) {
      int m = wr * 64 + i * 16 + l16;
      arh[i] = __builtin_bit_cast(bf16x8, *(const int4*)&s_ah[m * 40 + quad * 8]);
      arl[i] = __builtin_bit_cast(bf16x8, *(const int4*)&s_al[m * 40 + quad * 8]);
    }
    #pragma unroll
    for (int j = 0; j < 4; ++j) {
      int nn = wc * 64 + j * 16 + l16;
      bf16x8 brh = __builtin_bit_cast(bf16x8, *(const int4*)&s_bh[nn * 40 + quad * 8]);
      bf16x8 brl = __builtin_bit_cast(bf16x8, *(const int4*)&s_bl[nn * 40 + quad * 8]);
      #pragma unroll
      for (int i = 0; i < 4; ++i) {
        acc[i][j] = __builtin_amdgcn_mfma_f32_16x16x32_bf16(arh[i], brh, acc[i][j], 0, 0, 0);
        acc[i][j] = __builtin_amdgcn_mfma_f32_16x16x32_bf16(arh[i], brl, acc[i][j], 0, 0, 0);
        acc[i][j] = __builtin_amdgcn_mfma_f32_16x16x32_bf16(arl[i], brh, acc[i][j], 0, 0, 0);
      }
    }
    __syncthreads();
  }

  #pragma unroll
  for (int i = 0; i < 4; ++i)
    #pragma unroll
    for (int j = 0; j < 4; ++j) {
      int row = row0 + wr * 64 + i * 16 + quad * 4;
      int col = col0 + wc * 64 + j * 16 + l16;
      #pragma unroll
      for (int r = 0; r < 4; ++r)
        outp[(size_t)(row + r) * 1024 + col] = acc[i][j][r];
    }
}

// xg = sum_z p[z] + (b_ih + b_hh)
__global__ __launch_bounds__(256) void reduce_xg(
    const float* __restrict__ p, const float* __restrict__ b_ih,
    const float* __restrict__ b_hh, float* __restrict__ xg)
{
  int i = blockIdx.x * 256 + threadIdx.x;
  float4 s = {0.f, 0.f, 0.f, 0.f};
  #pragma unroll
  for (int z = 0; z < 8; ++z) {
    float4 a = ((const float4*)p)[(size_t)z * 262144 + i];
    s.x += a.x; s.y += a.y; s.z += a.z; s.w += a.w;
  }
  int cb = i & 255;
  float4 bi = ((const float4*)b_ih)[cb];
  float4 bh = ((const float4*)b_hh)[cb];
  float4 o;
  o.x = s.x + bi.x + bh.x;
  o.y = s.y + bi.y + bh.y;
  o.z = s.z + bi.z + bh.z;
  o.w = s.w + bi.w + bh.w;
  ((float4*)xg)[i] = o;
}

// ---------------- persistent LSTM recurrence ----------------
// R18 exact (measured best, 94.5us): 128 blocks = 16 b x 8 j-chunks of 32,
// tid=r*8+q, 1 poller/word (8 pollers/word contention -- free), 2 barriers/
// step. Weight float4 loads issued+pinned at the TOP of each step (the 12
// non-polling waves overlap their loads with the poll naturally; vmcnt is
// in-order so no further in-wave overlap is possible -- R19 proved trying
// costs 2.8x). Owner-lane activations; single-tanh serial combine.
__global__ __launch_bounds__(1024) void lstm_kernel(
    const float* __restrict__ xg, const float* __restrict__ w_hh,
    float* __restrict__ hs, unsigned long long* __restrict__ hpair)
{
  const int b = blockIdx.x & 15;
  const int c = blockIdx.x >> 4;        // j-chunk 0..7
  const int tid = threadIdx.x;
  const int r = tid >> 3;               // 0..127 = gate*32 + jl
  const int q = tid & 7;                // K-eighth
  const int gate = r >> 5;              // wave-uniform
  const int jl = r & 31;
  const int j = c * 32 + jl;            // global column 0..255

  const float4* wrow = (const float4*)(w_hh + ((size_t)(gate * 256 + j)) * 256 + q * 32);

  __shared__ float s_h2[8][36];          // [q][k], +4 pad -> distinct bank-quads
  __shared__ float s_gates[4][33];       // [gate][jl], ACTIVATED values
  float c_reg = 0.f;

  for (int s = 0; s < 64; ++s) {
    // 1) issue the 8 invariant weight loads NOW; pin so they can't sink.
    float4 wv[8];
    #pragma unroll
    for (int k = 0; k < 8; ++k) wv[k] = wrow[k];
    #pragma unroll
    for (int k = 0; k < 8; ++k)
      asm volatile("" : "+v"(wv[k].x), "+v"(wv[k].y), "+v"(wv[k].z), "+v"(wv[k].w));

    // 2) xg prefetch (independent of h)
    float xv = 0.f;
    if (q == 0) xv = xg[(size_t)(s * 16 + b) * 1024 + gate * 256 + j];

    float gv = 0.f;
    if (s > 0) {
      // 3) poll h(s-1): tid<256, 1 poller/word
      if (tid < 256) {
        const unsigned long long* src = hpair + ((size_t)(s - 1) * 16 + b) * 256 + tid;
        unsigned long long pv;
        do {
          pv = __hip_atomic_load(src, __ATOMIC_RELAXED, __HIP_MEMORY_SCOPE_AGENT);
        } while ((unsigned int)(pv >> 32) != (unsigned int)s);
        s_h2[tid >> 5][tid & 31] = __uint_as_float((unsigned int)pv);
      }
      __syncthreads();
      // 4) matvec
      const float4* hp = (const float4*)&s_h2[q][0];
      float p = 0.f;
      #pragma unroll
      for (int k = 0; k < 8; ++k) {
        float4 h4 = hp[k];
        p = fmaf(h4.x, wv[k].x, p);
        p = fmaf(h4.y, wv[k].y, p);
        p = fmaf(h4.z, wv[k].z, p);
        p = fmaf(h4.w, wv[k].w, p);
      }
      p += __shfl_xor(p, 1);
      p += __shfl_xor(p, 2);
      p += __shfl_xor(p, 4);
      gv = p;
    } else {
      __syncthreads();   // uniform barrier count
    }
    // 5) owner-lane activation (gate wave-uniform -> branchless per wave)
    if (q == 0) {
      float pre = gv + xv;
      s_gates[gate][jl] = (gate == 2) ? ftanh_(pre) : fsig_(pre);
    }
    __syncthreads();
    // 6) combine: one tanh on the serial chain
    if (tid < 32) {
      float si = s_gates[0][tid], sf = s_gates[1][tid];
      float tg = s_gates[2][tid], so = s_gates[3][tid];
      float cn = sf * c_reg + si * tg;
      c_reg = cn;
      float hv = so * ftanh_(cn);
      hs[(size_t)s * 4096 + b * 256 + c * 32 + tid] = hv;
      unsigned long long pv =
          ((unsigned long long)(unsigned int)(s + 1) << 32) | __float_as_uint(hv);
      __hip_atomic_store(hpair + ((size_t)s * 16 + b) * 256 + c * 32 + tid, pv,
                         __ATOMIC_RELAXED, __HIP_MEMORY_SCOPE_AGENT);
    }
  }
}

// ---------------- classifier head ----------------
__global__ __launch_bounds__(64) void cls_kernel(
    const float* __restrict__ hs, const float* __restrict__ cw,
    const float* __restrict__ cb, float* __restrict__ out)
{
  const int id = blockIdx.x;
  const int b = id / 53;
  const int t = id % 53;
  const int s = 11 + t;
  const int lane = threadIdx.x;
  float4 hv = ((const float4*)(hs + (size_t)s * 4096 + b * 256))[lane];
  float4 wv = ((const float4*)cw)[lane];
  float p = hv.x * wv.x + hv.y * wv.y + hv.z * wv.z + hv.w * wv.w;
  #pragma unroll
  for (int off = 32; off >= 1; off >>= 1) p += __shfl_xor(p, off);
  if (lane == 0) out[id] = tanhf(p + cb[0]);
}

// ---------------------------------------------------------------------------
extern "C" void kernel_launch(void* const* d_in, const int* in_sizes, int n_in,
                              void* d_out, int out_size, void* d_ws, size_t ws_size,
                              hipStream_t stream)
{
  (void)in_sizes; (void)n_in; (void)out_size; (void)ws_size;
  const float* imgs = (const float*)d_in[0];
  const float* w_ih  = (const float*)d_in[31];
  const float* w_hh  = (const float*)d_in[32];
  const float* b_ih  = (const float*)d_in[33];
  const float* b_hh  = (const float*)d_in[34];
  const float* cls_w = (const float*)d_in[35];
  const float* cls_b = (const float*)d_in[36];
  float* out = (float*)d_out;

  float* ws   = (float*)d_ws;
  float* actA = ws;
  float* actB = actA + 16777216;
  float* xg   = actB + 16777216;
  float* hs   = xg + 1048576;
  unsigned long long* hpair = (unsigned long long*)(hs + 262144);
  float* wfp  = hs + 262144 + 524288;
  static const int ocs[6] = {16, 16, 32, 32, 64, 64};
  static const int ics[6] = {3, 16, 16, 32, 32, 64};
  float* wf[6];
  size_t off = 0;
  for (int i = 0; i < 6; ++i) { wf[i] = wfp + off; off += (size_t)ocs[i] * ics[i] * 12; }
  float* biasp = wfp + off;
  float* bias[6];
  for (int i = 0; i < 6; ++i) bias[i] = biasp + i * 64;

  // packed MFMA weights (L1..L5): sizes MT*KG*512 ushorts per plane
  static const int psz[5] = {2560, 5120, 9216, 18432, 36864};
  unsigned short* WH = (unsigned short*)(biasp + 6 * 64);
  unsigned short* WL = WH + 72192;
  unsigned short *wh[5], *wl[5];
  {
    int o = 0;
    for (int i = 0; i < 5; ++i) { wh[i] = WH + o; wl[i] = WL + o; o += psz[i]; }
  }

  float* partials = actA;       // reused post-conv
  unsigned short* Ah = (unsigned short*)(actA + 8388608);
  unsigned short* Al = Ah + 4194304;
  unsigned short* Bh = Al + 4194304;
  unsigned short* Bl = Bh + 4194304;

  FoldPack fp;
  for (int i = 0; i < 6; ++i) {
    fp.w[i] = (const float*)d_in[1 + 5*i];
    fp.g[i] = (const float*)d_in[2 + 5*i];
    fp.b[i] = (const float*)d_in[3 + 5*i];
    fp.m[i] = (const float*)d_in[4 + 5*i];
    fp.v[i] = (const float*)d_in[5 + 5*i];
    fp.wf[i] = wf[i];
    fp.bias[i] = bias[i];
    fp.oc[i] = ocs[i];
    fp.ic[i] = ics[i];
  }
  fold_all<<<dim3(8, 6), 256, 0, stream>>>(fp);

  PackPack pp;
  static const int kgs[5] = {5, 5, 9, 9, 18};
  static const int krs[5] = {144, 144, 288, 288, 576};
  for (int i = 0; i < 5; ++i) {
    pp.w[i] = (const float*)d_in[1 + 5*(i+1)];
    pp.g[i] = (const float*)d_in[2 + 5*(i+1)];
    pp.v[i] = (const float*)d_in[5 + 5*(i+1)];
    pp.wh[i] = wh[i];
    pp.wl[i] = wl[i];
    pp.ic[i] = ics[i+1];
    pp.oc[i] = ocs[i+1];
    pp.kg[i] = kgs[i];
    pp.kreal[i] = krs[i];
  }
  pack_w<<<dim3(36, 5), 256, 0, stream>>>(pp);

  // L0 fp32 direct conv
  conv_bn_relu<3, 16, 64, 64, 2, 4, 2, 1, 4><<<2048, 256, 0, stream>>>(imgs, wf[0], bias[0], actA);
  //            IC  OC  IH  IW  S SPL KG ZR OS
  conv_mfma<16, 16, 32, 32, 1, 4, 5, 1, 0><<<4096, 256, 0, stream>>>(actA, wh[0], wl[0], bias[1], actB, nullptr, nullptr);
  conv_mfma<16, 32, 32, 32, 2, 4, 5, 1, 0><<<4096, 256, 0, stream>>>(actB, wh[1], wl[1], bias[2], actA, nullptr, nullptr);
  conv_mfma<32, 32, 16, 16, 1, 1, 9, 0, 0><<<1024, 256, 0, stream>>>(actA, wh[2], wl[2], bias[3], actB, nullptr, nullptr);
  conv_mfma<32, 64, 16, 16, 2, 1, 9, 0, 0><<<1024, 256, 0, stream>>>(actB, wh[3], wl[3], bias[4], actA, nullptr, nullptr);
  // L5: epilogue writes Ah/Al directly (split_a fused; actB unused)
  conv_mfma<64, 64,  8,  8, 1, 1, 18, 0, 1><<<1024, 256, 0, stream>>>(actA, wh[4], wl[4], bias[5], actB, Ah, Al);

  split_b<<<4096, 256, 0, stream>>>(w_ih, Bh, Bl);
  mfma_xg<<<dim3(8, 8, 8), 256, 0, stream>>>(Ah, Al, Bh, Bl, partials);
  reduce_xg<<<1024, 256, 0, stream>>>(partials, b_ih, b_hh, xg);
  lstm_kernel<<<128, 1024, 0, stream>>>(xg, w_hh, hs, hpair);
  cls_kernel<<<848, 64, 0, stream>>>(hs, cls_w, cls_b, out);
}